// Round 4
// baseline (91.062 us; speedup 1.0000x reference)
//
#include <hip/hip_runtime.h>
#include <math.h>

// Problem constants (fixed by reference setup_inputs): x [2,3,512,512] f32.
#define BC 6
#define H_ 512
#define W_ 512
#define HW (H_ * W_)
#define EPS 1e-6f
#define EXPM05 0.60653065971263342f  // exp(-0.5)

#define TW 72      // tile width  (64 outputs + 2*4 halo)
#define TH 24      // tile height (16 outputs + 2*4 halo)
#define XSS 26     // xs column stride (gcd(26,32)=2 -> conflict-free-ish b64)
#define VHS 74     // vh row stride: slot 0 = prefix zero, 1..72 = cols, 73 pad; gcd(74/2=37.. (74 mod 32)=10, gcd2 ok

// vh rows: pair round sr = stat*4 + (R-1) (stat 0=S1, 1=S2) -> 8 sr x 16 o = 128 rows.
// entropy round reuses rows sr = R-1 (0..3) x 16 o = 64 rows.
__global__ __launch_bounds__(512, 6) void texmart_kernel(const float* __restrict__ x,
                                                         float* __restrict__ out) {
    __shared__ float xs[TW][XSS];        // 7.5 KB, [col][row]
    __shared__ float vh[128 * VHS];      // 37.9 KB

    const int tx = threadIdx.x, ty = threadIdx.y;
    const int tid = ty * 64 + tx;
    const int bx = blockIdx.x * 64, by = blockIdx.y * 16;
    const int plane = blockIdx.z;
    const float* __restrict__ xp = x + (size_t)plane * HW;

    // ---------------- A: stage tile (zero pad) ----------------
    for (int idx = tid; idx < TW * TH; idx += 512) {
        const int t = idx / TW, c = idx - t * TW;
        const int gy = by + t - 4, gx = bx + c - 4;
        float v = 0.f;
        if (gy >= 0 && gy < H_ && gx >= 0 && gx < W_) v = xp[gy * W_ + gx];
        xs[c][t] = v;
    }
    __syncthreads();

    // ---------------- B12: vertical window sums for S1 (p) and S2 (p^2) ----------------
    if (tid < 288) {
        const int c = tid % 72;
        const int r2 = tid / 72;             // 0..3
        const int stat = r2 & 1;
        const int oh = (r2 >> 1) * 8;        // o-half base: 0 or 8
        float PL[17]; PL[0] = 0.f;
        const float* col = &xs[c][oh];       // rows oh..oh+15 cover windows for o in [oh,oh+7]
#pragma unroll
        for (int i = 0; i < 8; ++i) {
            const float2 u = *(const float2*)(col + 2 * i);
            if (stat == 0) {
                PL[2 * i + 1] = PL[2 * i] + u.x;
                PL[2 * i + 2] = PL[2 * i + 1] + u.y;
            } else {
                PL[2 * i + 1] = __fmaf_rn(u.x, u.x, PL[2 * i]);
                PL[2 * i + 2] = __fmaf_rn(u.y, u.y, PL[2 * i + 1]);
            }
        }
#pragma unroll
        for (int op = 0; op < 8; ++op) {
#pragma unroll
            for (int R = 1; R <= 4; ++R) {
                // vertical window rows [o+4-R, o+4+R], local = abs - oh
                vh[((stat * 4 + R - 1) * 16 + oh + op) * VHS + (c + 1)] =
                    PL[op + 5 + R] - PL[op + 4 - R];
            }
        }
    }
    __syncthreads();

    // ---------------- C12: in-place horizontal prefix per row ----------------
    if (tid < 128) {
        float* base = vh + tid * VHS;
        float run = 0.f;
#pragma unroll
        for (int i = 0; i < 37; ++i) {
            const float2 e = *(const float2*)(base + 2 * i);
            float n0, n1;
            if (i == 0) { n0 = 0.f; run = e.y; n1 = run; }        // P[0]=0, P[1]=V[1]
            else {
                run += e.x; n0 = run;
                if (i < 36) { run += e.y; n1 = run; } else { n1 = 0.f; }  // slot 73 unused
            }
            *(float2*)(base + 2 * i) = make_float2(n0, n1);
        }
    }
    __syncthreads();

    // ---------------- D12: window sums via prefix diff; contrast+energy out ----------------
    // P[k] = sum V[1..k] (V slot c+1 = tile col c) -> sum cols [a,b] = P[b+1]-P[a].
    // Window cols [tx+4-R, tx+4+R] -> P[tx+5+R] - P[tx+4-R].
    float mean[2][4];
    const int gxx = bx + tx;
#pragma unroll
    for (int oi = 0; oi < 2; ++oi) {
        const int o = ty * 2 + oi;
        float S1[4], S2[4];
#pragma unroll
        for (int R = 1; R <= 4; ++R) {
            const float* r1 = vh + (((R - 1)) * 16 + o) * VHS;
            const float* r2p = vh + ((4 + R - 1) * 16 + o) * VHS;
            S1[R - 1] = r1[tx + 5 + R] - r1[tx + 4 - R];
            S2[R - 1] = r2p[tx + 5 + R] - r2p[tx + 4 - R];
        }
        float* orow = out + (size_t)plane * 16 * HW + (size_t)(by + o) * W_ + gxx;
#pragma unroll
        for (int R = 1; R <= 4; ++R) {
            const float K = (float)((2 * R + 1) * (2 * R + 1));
            const float invK = 1.f / K;
            const float invKm1 = 1.f / (K - 1.f);
            const float m = S1[R - 1] * invK;
            mean[oi][R - 1] = m;
            float S2c = __fmaf_rn(-S1[R - 1], m, S2[R - 1]);   // Σ(p-mean)^2
            if (S2c < 0.f) S2c = 0.f;
            const float sd = sqrtf(S2c * invKm1) + EPS;        // ddof=1 std + EPS
            const float contrast = (S2c * invK) * __frcp_rn(sd * sd);
            const float energy = S2[R - 1] * invK;
            float* o4 = orow + (size_t)(R - 1) * 4 * HW;
            o4[0 * HW] = (contrast + EPS) * EXPM05;   // exp(log(f+EPS)-0.5)
            o4[1 * HW] = (energy + EPS) * EXPM05;
        }
    }
    __syncthreads();   // WAR: vh about to be overwritten

    // ---------------- B3: vertical window sums for SL (p*log(p+EPS)) ----------------
    if (tid < 144) {
        const int c = tid % 72;
        const int oh = (tid / 72) * 8;
        float PL[17]; PL[0] = 0.f;
        const float* col = &xs[c][oh];
#pragma unroll
        for (int i = 0; i < 8; ++i) {
            const float2 u = *(const float2*)(col + 2 * i);
            const float q0 = u.x * __logf(u.x + EPS);   // zero-pad -> exactly 0
            const float q1 = u.y * __logf(u.y + EPS);
            PL[2 * i + 1] = PL[2 * i] + q0;
            PL[2 * i + 2] = PL[2 * i + 1] + q1;
        }
#pragma unroll
        for (int op = 0; op < 8; ++op) {
#pragma unroll
            for (int R = 1; R <= 4; ++R) {
                vh[((R - 1) * 16 + oh + op) * VHS + (c + 1)] = PL[op + 5 + R] - PL[op + 4 - R];
            }
        }
    }
    __syncthreads();

    // ---------------- C3: prefix rows 0..63 ----------------
    if (tid < 64) {
        float* base = vh + tid * VHS;
        float run = 0.f;
#pragma unroll
        for (int i = 0; i < 37; ++i) {
            const float2 e = *(const float2*)(base + 2 * i);
            float n0, n1;
            if (i == 0) { n0 = 0.f; run = e.y; n1 = run; }
            else {
                run += e.x; n0 = run;
                if (i < 36) { run += e.y; n1 = run; } else { n1 = 0.f; }
            }
            *(float2*)(base + 2 * i) = make_float2(n0, n1);
        }
    }
    __syncthreads();

    // ---------------- D3: entropy out ----------------
#pragma unroll
    for (int oi = 0; oi < 2; ++oi) {
        const int o = ty * 2 + oi;
        float* orow = out + (size_t)plane * 16 * HW + (size_t)(by + o) * W_ + gxx;
#pragma unroll
        for (int R = 1; R <= 4; ++R) {
            const float* rl = vh + ((R - 1) * 16 + o) * VHS;
            const float SL = rl[tx + 5 + R] - rl[tx + 4 - R];
            const float K = (float)((2 * R + 1) * (2 * R + 1));
            const float entropy = -SL * (1.f / K);
            orow[(size_t)(R - 1) * 4 * HW + 2 * HW] = (entropy + EPS) * EXPM05;
        }
    }

    // ---------------- E: homogeneity (reads xs only; no barrier needed) ----------------
    float sa[2][4];
#pragma unroll
    for (int oi = 0; oi < 2; ++oi)
#pragma unroll
        for (int R = 0; R < 4; ++R) sa[oi][R] = 0.f;

#pragma unroll
    for (int dj = 0; dj < 9; ++dj) {
        const int a = dj < 4 ? 4 - dj : dj - 4;
        const float* col = &xs[tx + dj][ty * 2];
        const float2 u0 = *(const float2*)(col + 0);
        const float2 u1 = *(const float2*)(col + 2);
        const float2 u2 = *(const float2*)(col + 4);
        const float2 u3 = *(const float2*)(col + 6);
        const float2 u4 = *(const float2*)(col + 8);
        const float p[10] = {u0.x, u0.y, u1.x, u1.y, u2.x, u2.y, u3.x, u3.y, u4.x, u4.y};

#pragma unroll
        for (int oi = 0; oi < 2; ++oi) {
#pragma unroll
            for (int k = 0; k < 9; ++k) {
                const int adi = k < 4 ? 4 - k : k - 4;
                const int rm = a > adi ? a : adi;
                const int r0 = rm < 1 ? 1 : rm;      // compile-time after unroll
#pragma unroll
                for (int R = 1; R <= 4; ++R) {
                    if (R >= r0) sa[oi][R - 1] += fabsf(p[oi + k] - mean[oi][R - 1]);
                }
            }
        }
    }

#pragma unroll
    for (int oi = 0; oi < 2; ++oi) {
        const int o = ty * 2 + oi;
        float* orow = out + (size_t)plane * 16 * HW + (size_t)(by + o) * W_ + gxx;
#pragma unroll
        for (int R = 1; R <= 4; ++R) {
            const float K = (float)((2 * R + 1) * (2 * R + 1));
            const float homog = __frcp_rn(1.f + sa[oi][R - 1] * (1.f / K));
            orow[(size_t)(R - 1) * 4 * HW + 3 * HW] = (homog + EPS) * EXPM05;
        }
    }
}

extern "C" void kernel_launch(void* const* d_in, const int* in_sizes, int n_in,
                              void* d_out, int out_size, void* d_ws, size_t ws_size,
                              hipStream_t stream) {
    const float* x = (const float*)d_in[0];
    float* out = (float*)d_out;
    dim3 block(64, 8, 1);
    dim3 grid(W_ / 64, H_ / 16, BC);
    texmart_kernel<<<grid, block, 0, stream>>>(x, out);
}

// Round 5
// 66.274 us; speedup vs baseline: 1.3740x; 1.3740x over previous
//
#include <hip/hip_runtime.h>
#include <math.h>

// Problem constants (fixed by reference setup_inputs): x [2,3,512,512] f32.
#define BC 6
#define H_ 512
#define W_ 512
#define HW (H_ * W_)
#define EPS 1e-6f
#define EXPM05 0.60653065971263342f  // exp(-0.5)

#define TW 72    // tile cols (64 outputs + 8 halo)
#define TH 24    // tile rows (16 outputs + 8 halo)
#define XSS 26   // xs column stride (floats)
#define VHS 72   // vh row stride: col c at slot c

// Block 64x8 = 512 threads -> 64x16 output tile. Per-R rounds:
//   B_R: 1152 column-units (col c, out-row o) widen running vertical sums
//        s1,s2,sl by rows o+4±R and publish V_R to vh[stat*16+o][c].
//   D_R: each thread sums (2R+1) V values per stat (stride-1 LDS reads),
//        computes contrast/energy/entropy for 2 pixels, stores, keeps mean.
//   E:   homogeneity pass (non-separable), round-3-proven access pattern.
__global__ __launch_bounds__(512, 6) void texmart_kernel(const float* __restrict__ x,
                                                         float* __restrict__ out) {
    __shared__ float xs[TW][XSS];    // [col][row], 7488 B
    __shared__ float vh[48][VHS];    // [stat*16+o][col], 13824 B

    const int tx = threadIdx.x, ty = threadIdx.y;
    const int tid = ty * 64 + tx;
    const int bx = blockIdx.x * 64, by = blockIdx.y * 16;
    const int plane = blockIdx.z;
    const float* __restrict__ xp = x + (size_t)plane * HW;

    // ---------------- A: stage tile (zero pad) ----------------
    for (int idx = tid; idx < TW * TH; idx += 512) {
        const int t = idx / TW, c = idx - t * TW;
        const int gy = by + t - 4, gx = bx + c - 4;
        float v = 0.f;
        if (gy >= 0 && gy < H_ && gx >= 0 && gx < W_) v = xp[gy * W_ + gx];
        xs[c][t] = v;
    }
    __syncthreads();

    // ---------------- unit setup + center-row init ----------------
    int uoA[3], ucA[3];
    float s1A[3], s2A[3], slA[3];
#pragma unroll
    for (int i = 0; i < 3; ++i) {
        const int u = tid + i * 512;
        const int uu = (u < 1152) ? u : 0;        // i==2 only valid for tid<128
        const int o = uu / 72, c = uu - o * 72;
        uoA[i] = o; ucA[i] = c;
        const float pc = xs[c][o + 4];
        s1A[i] = pc;
        s2A[i] = pc * pc;
        slA[i] = pc * __logf(pc + EPS);
    }

    float mean[2][4];
    const int gxx = bx + tx;
    float* __restrict__ obase = out + (size_t)plane * 16 * HW + (size_t)by * W_ + gxx;

    // ---------------- per-R rounds ----------------
#pragma unroll
    for (int R = 1; R <= 4; ++R) {
        // B_R: widen vertical sums, publish V_R.
#pragma unroll
        for (int i = 0; i < 3; ++i) {
            if (i < 2 || tid < 128) {
                const int o = uoA[i], c = ucA[i];
                const float plo = xs[c][o + 4 - R];
                const float phi = xs[c][o + 4 + R];
                s1A[i] += plo + phi;
                s2A[i] = __fmaf_rn(plo, plo, __fmaf_rn(phi, phi, s2A[i]));
                slA[i] += plo * __logf(plo + EPS) + phi * __logf(phi + EPS);
                vh[o][c]      = s1A[i];
                vh[16 + o][c] = s2A[i];
                vh[32 + o][c] = slA[i];
            }
        }
        __syncthreads();

        // D_R: horizontal window sums + 3 features out.
        const float K = (float)((2 * R + 1) * (2 * R + 1));
        const float invK = 1.f / K;
        const float invKm1 = 1.f / (K - 1.f);
#pragma unroll
        for (int oi = 0; oi < 2; ++oi) {
            const int o = ty * 2 + oi;
            float S1 = 0.f, S2 = 0.f, SL = 0.f;
#pragma unroll
            for (int s = -4; s <= 4; ++s) {
                if (s >= -R && s <= R) {          // compile-time after unroll
                    S1 += vh[o][tx + 4 + s];
                    S2 += vh[16 + o][tx + 4 + s];
                    SL += vh[32 + o][tx + 4 + s];
                }
            }
            const float m = S1 * invK;
            mean[oi][R - 1] = m;
            float S2c = __fmaf_rn(-S1, m, S2);            // Σ(p-mean)^2
            if (S2c < 0.f) S2c = 0.f;
            const float sd = sqrtf(S2c * invKm1) + EPS;   // ddof=1 std + EPS
            const float contrast = (S2c * invK) * __frcp_rn(sd * sd);
            const float energy = S2 * invK;
            const float entropy = -SL * invK;

            float* __restrict__ o4 = obase + (size_t)o * W_ + (size_t)(R - 1) * 4 * HW;
            o4[0 * HW] = (contrast + EPS) * EXPM05;   // exp(log(f+EPS)-0.5)
            o4[1 * HW] = (energy + EPS) * EXPM05;
            o4[2 * HW] = (entropy + EPS) * EXPM05;
        }
        if (R < 4) __syncthreads();   // WAR: next round's B overwrites vh
    }

    // ---------------- E: homogeneity (reads xs only; no barrier needed) ----------------
    const int ty2 = ty * 2;
    float sa[2][4];
#pragma unroll
    for (int oi = 0; oi < 2; ++oi)
#pragma unroll
        for (int R = 0; R < 4; ++R) sa[oi][R] = 0.f;

#pragma unroll
    for (int dj = 0; dj < 9; ++dj) {
        const int a = dj < 4 ? 4 - dj : dj - 4;
        const float* __restrict__ col = &xs[tx + dj][ty2];
        const float2 u0 = *(const float2*)(col + 0);
        const float2 u1 = *(const float2*)(col + 2);
        const float2 u2 = *(const float2*)(col + 4);
        const float2 u3 = *(const float2*)(col + 6);
        const float2 u4 = *(const float2*)(col + 8);
        const float p[10] = {u0.x, u0.y, u1.x, u1.y, u2.x, u2.y, u3.x, u3.y, u4.x, u4.y};

#pragma unroll
        for (int oi = 0; oi < 2; ++oi) {
#pragma unroll
            for (int k = 0; k < 9; ++k) {
                const int adi = k < 4 ? 4 - k : k - 4;
                const int rm = a > adi ? a : adi;
                const int r0 = rm < 1 ? 1 : rm;           // compile-time
#pragma unroll
                for (int R = 1; R <= 4; ++R) {
                    if (R >= r0) sa[oi][R - 1] += fabsf(p[oi + k] - mean[oi][R - 1]);
                }
            }
        }
    }

#pragma unroll
    for (int oi = 0; oi < 2; ++oi) {
        const int o = ty2 + oi;
#pragma unroll
        for (int R = 1; R <= 4; ++R) {
            const float K = (float)((2 * R + 1) * (2 * R + 1));
            const float homog = __frcp_rn(1.f + sa[oi][R - 1] * (1.f / K));
            obase[(size_t)o * W_ + (size_t)(R - 1) * 4 * HW + 3 * HW] =
                (homog + EPS) * EXPM05;
        }
    }
}

extern "C" void kernel_launch(void* const* d_in, const int* in_sizes, int n_in,
                              void* d_out, int out_size, void* d_ws, size_t ws_size,
                              hipStream_t stream) {
    const float* x = (const float*)d_in[0];
    float* out = (float*)d_out;
    dim3 block(64, 8, 1);
    dim3 grid(W_ / 64, H_ / 16, BC);
    texmart_kernel<<<grid, block, 0, stream>>>(x, out);
}

// Round 6
// 42.745 us; speedup vs baseline: 2.1303x; 1.5504x over previous
//
#include <hip/hip_runtime.h>
#include <math.h>

// Problem constants (fixed by reference setup_inputs): x [2,3,512,512] f32.
#define BC 6
#define H_ 512
#define W_ 512
#define HW (H_ * W_)
#define EPS 1e-6f
#define EXPM05 0.60653065971263342f  // exp(-0.5)

#define TW 72    // tile cols (64 outputs + 8 halo)
#define TH 24    // tile rows (16 outputs + 8 halo)
#define XSS 26   // xs column stride (floats)
#define VHS 72   // vh row stride: col c at slot c

// Block 64x8 = 512 threads -> 64x16 output tile. Per-R rounds:
//   B_R: 1152 column-units (col c, out-row o) widen running vertical sums
//        s1,s2,sl by rows o+4±R and publish V_R to vh[stat*16+o][c].
//   D_R: each thread sums (2R+1) V values per stat (stride-1 LDS reads),
//        computes contrast/energy/entropy for 2 pixels, stores, keeps mean.
//   E:   homogeneity pass (non-separable), round-3-proven access pattern.
// NOTE: no min-occupancy in launch_bounds — rounds 4/5 proved a second arg
// of 6 caps VGPR at 40 (48 waves/CU semantics) and forces catastrophic
// scratch spill (FETCH 70-117 MB vs 10 MB ideal).
__global__ __launch_bounds__(512) void texmart_kernel(const float* __restrict__ x,
                                                      float* __restrict__ out) {
    __shared__ float xs[TW][XSS];    // [col][row], 7488 B
    __shared__ float vh[48][VHS];    // [stat*16+o][col], 13824 B

    const int tx = threadIdx.x, ty = threadIdx.y;
    const int tid = ty * 64 + tx;
    const int bx = blockIdx.x * 64, by = blockIdx.y * 16;
    const int plane = blockIdx.z;
    const float* __restrict__ xp = x + (size_t)plane * HW;

    // ---------------- A: stage tile (zero pad) ----------------
    for (int idx = tid; idx < TW * TH; idx += 512) {
        const int t = idx / TW, c = idx - t * TW;
        const int gy = by + t - 4, gx = bx + c - 4;
        float v = 0.f;
        if (gy >= 0 && gy < H_ && gx >= 0 && gx < W_) v = xp[gy * W_ + gx];
        xs[c][t] = v;
    }
    __syncthreads();

    // ---------------- unit setup + center-row init ----------------
    int uoA[3], ucA[3];
    float s1A[3], s2A[3], slA[3];
#pragma unroll
    for (int i = 0; i < 3; ++i) {
        const int u = tid + i * 512;
        const int uu = (u < 1152) ? u : 0;        // i==2 only valid for tid<128
        const int o = uu / 72, c = uu - o * 72;
        uoA[i] = o; ucA[i] = c;
        const float pc = xs[c][o + 4];
        s1A[i] = pc;
        s2A[i] = pc * pc;
        slA[i] = pc * __logf(pc + EPS);
    }

    float mean[2][4];
    const int gxx = bx + tx;
    float* __restrict__ obase = out + (size_t)plane * 16 * HW + (size_t)by * W_ + gxx;

    // ---------------- per-R rounds ----------------
#pragma unroll
    for (int R = 1; R <= 4; ++R) {
        // B_R: widen vertical sums, publish V_R.
#pragma unroll
        for (int i = 0; i < 3; ++i) {
            if (i < 2 || tid < 128) {
                const int o = uoA[i], c = ucA[i];
                const float plo = xs[c][o + 4 - R];
                const float phi = xs[c][o + 4 + R];
                s1A[i] += plo + phi;
                s2A[i] = __fmaf_rn(plo, plo, __fmaf_rn(phi, phi, s2A[i]));
                slA[i] += plo * __logf(plo + EPS) + phi * __logf(phi + EPS);
                vh[o][c]      = s1A[i];
                vh[16 + o][c] = s2A[i];
                vh[32 + o][c] = slA[i];
            }
        }
        __syncthreads();

        // D_R: horizontal window sums + 3 features out.
        const float K = (float)((2 * R + 1) * (2 * R + 1));
        const float invK = 1.f / K;
        const float invKm1 = 1.f / (K - 1.f);
#pragma unroll
        for (int oi = 0; oi < 2; ++oi) {
            const int o = ty * 2 + oi;
            float S1 = 0.f, S2 = 0.f, SL = 0.f;
#pragma unroll
            for (int s = -4; s <= 4; ++s) {
                if (s >= -R && s <= R) {          // compile-time after unroll
                    S1 += vh[o][tx + 4 + s];
                    S2 += vh[16 + o][tx + 4 + s];
                    SL += vh[32 + o][tx + 4 + s];
                }
            }
            const float m = S1 * invK;
            mean[oi][R - 1] = m;
            float S2c = __fmaf_rn(-S1, m, S2);            // Σ(p-mean)^2
            if (S2c < 0.f) S2c = 0.f;
            const float sd = sqrtf(S2c * invKm1) + EPS;   // ddof=1 std + EPS
            const float contrast = (S2c * invK) * __frcp_rn(sd * sd);
            const float energy = S2 * invK;
            const float entropy = -SL * invK;

            float* __restrict__ o4 = obase + (size_t)o * W_ + (size_t)(R - 1) * 4 * HW;
            o4[0 * HW] = (contrast + EPS) * EXPM05;   // exp(log(f+EPS)-0.5)
            o4[1 * HW] = (energy + EPS) * EXPM05;
            o4[2 * HW] = (entropy + EPS) * EXPM05;
        }
        if (R < 4) __syncthreads();   // WAR: next round's B overwrites vh
    }

    // ---------------- E: homogeneity (reads xs only; no barrier needed) ----------------
    const int ty2 = ty * 2;
    float sa[2][4];
#pragma unroll
    for (int oi = 0; oi < 2; ++oi)
#pragma unroll
        for (int R = 0; R < 4; ++R) sa[oi][R] = 0.f;

#pragma unroll
    for (int dj = 0; dj < 9; ++dj) {
        const int a = dj < 4 ? 4 - dj : dj - 4;
        const float* __restrict__ col = &xs[tx + dj][ty2];
        const float2 u0 = *(const float2*)(col + 0);
        const float2 u1 = *(const float2*)(col + 2);
        const float2 u2 = *(const float2*)(col + 4);
        const float2 u3 = *(const float2*)(col + 6);
        const float2 u4 = *(const float2*)(col + 8);
        const float p[10] = {u0.x, u0.y, u1.x, u1.y, u2.x, u2.y, u3.x, u3.y, u4.x, u4.y};

#pragma unroll
        for (int oi = 0; oi < 2; ++oi) {
#pragma unroll
            for (int k = 0; k < 9; ++k) {
                const int adi = k < 4 ? 4 - k : k - 4;
                const int rm = a > adi ? a : adi;
                const int r0 = rm < 1 ? 1 : rm;           // compile-time
#pragma unroll
                for (int R = 1; R <= 4; ++R) {
                    if (R >= r0) sa[oi][R - 1] += fabsf(p[oi + k] - mean[oi][R - 1]);
                }
            }
        }
    }

#pragma unroll
    for (int oi = 0; oi < 2; ++oi) {
        const int o = ty2 + oi;
#pragma unroll
        for (int R = 1; R <= 4; ++R) {
            const float K = (float)((2 * R + 1) * (2 * R + 1));
            const float homog = __frcp_rn(1.f + sa[oi][R - 1] * (1.f / K));
            obase[(size_t)o * W_ + (size_t)(R - 1) * 4 * HW + 3 * HW] =
                (homog + EPS) * EXPM05;
        }
    }
}

extern "C" void kernel_launch(void* const* d_in, const int* in_sizes, int n_in,
                              void* d_out, int out_size, void* d_ws, size_t ws_size,
                              hipStream_t stream) {
    const float* x = (const float*)d_in[0];
    float* out = (float*)d_out;
    dim3 block(64, 8, 1);
    dim3 grid(W_ / 64, H_ / 16, BC);
    texmart_kernel<<<grid, block, 0, stream>>>(x, out);
}